// Round 3
// baseline (1285.376 us; speedup 1.0000x reference)
//
#include <hip/hip_runtime.h>
#include <hip/hip_cooperative_groups.h>
#include <cstddef>

namespace cg = cooperative_groups;

#define NB 32
#define NN 2000
#define NRD 32
#define NE 128
#define NH 256
#define NA 8
#define KP 2016          // conv K padded to multiple of 32
#define ACTION_NORM 2000.0f

typedef unsigned short u16;
typedef __bf16 b16x8 __attribute__((ext_vector_type(8)));
typedef float f32x4 __attribute__((ext_vector_type(4)));
typedef const __attribute__((address_space(1))) unsigned int* gptr_t;
typedef __attribute__((address_space(3))) unsigned int* lptr_t;

__device__ inline u16 f2bf(float x) {
    unsigned u = __float_as_uint(x);
    u += 0x7FFFu + ((u >> 16) & 1u);
    return (u16)(u >> 16);
}
__device__ inline float bf2f(u16 h) { return __uint_as_float((unsigned)h << 16); }

// ---------------------------------------------------------------- init: dmax/s1/s2 reset, actions, ap for agent 0
__global__ __launch_bounds__(256) void k_init(unsigned* dmax_u, float* actions, float* ap,
                                              float* s1, float* s2,
                                              const int* __restrict__ fa,
                                              const int* __restrict__ fid,
                                              const float* __restrict__ Wq1) {
    const int b = blockIdx.x, t = threadIdx.x;   // 32 blocks x 256
    __shared__ float act[NA];
    if (b == 0 && t == 0) *dmax_u = 0u;
    if (t == 0) { s1[b] = 0.0f; s2[b] = 0.0f; }
    if (t < NA) {
        float v = -1.0f;
        for (int j = 0; j < 3; ++j)
            if (fid[j] == t) v = (float)fa[j * NB + b] / ACTION_NORM;
        act[t] = v;
        actions[b * NA + t] = v;
    }
    __syncthreads();
    float s = 0.0f;
#pragma unroll
    for (int a = 0; a < NA; ++a) s = fmaf(act[a], Wq1[(size_t)(NE + a) * NH + t], s);
    ap[b * NH + t] = s;
}

// ---------------------------------------------------------------- global max of dm
__global__ __launch_bounds__(256) void k_max(const float* __restrict__ dm,
                                             unsigned* dmax_u, int n) {
    __shared__ float sh[256];
    float m = 0.0f;
    for (int i = blockIdx.x * blockDim.x + threadIdx.x; i < n; i += gridDim.x * blockDim.x)
        m = fmaxf(m, dm[i]);
    sh[threadIdx.x] = m; __syncthreads();
    for (int s = 128; s > 0; s >>= 1) {
        if (threadIdx.x < s) sh[threadIdx.x] = fmaxf(sh[threadIdx.x], sh[threadIdx.x + s]);
        __syncthreads();
    }
    if (threadIdx.x == 0) atomicMax(dmax_u, __float_as_uint(sh[0]));
}

// ---------------------------------------------------------------- sim rows -> bf16 (K padded), inv rowsum
__global__ __launch_bounds__(256) void k_sim(const float* __restrict__ dm,
                                             const unsigned* __restrict__ dmax_u,
                                             u16* __restrict__ simb,
                                             float* __restrict__ inv_rs) {
    __shared__ float sh[256];
    const int n = blockIdx.x;
    const float inv = 1.0f / __uint_as_float(*dmax_u);
    float s = 0.0f;
    for (int m = threadIdx.x; m < KP; m += 256) {
        if (m < NN) {
            float e = expf(-dm[(size_t)n * NN + m] * inv);
            simb[(size_t)n * KP + m] = f2bf(e);
            s += e;
        } else {
            simb[(size_t)n * KP + m] = 0;
        }
    }
    sh[threadIdx.x] = s; __syncthreads();
    for (int st = 128; st > 0; st >>= 1) {
        if (threadIdx.x < st) sh[threadIdx.x] += sh[threadIdx.x + st];
        __syncthreads();
    }
    if (threadIdx.x == 0) inv_rs[n] = 1.0f / sh[0];
}

// ---------------------------------------------------------------- prep: convert state, transpose weights, zero ENC pad
#define PREP_STATE (64000 * 32)
#define PREP_W1T   (256 * 32)
#define PREP_W2T   (128 * 256)
#define PREP_WQ1T  (256 * 128)
#define PREP_PAD   (4096 * 16)
#define PREP_TOT   (PREP_STATE + PREP_W1T + PREP_W2T + PREP_WQ1T + PREP_PAD)
__global__ __launch_bounds__(256) void k_prep(const float* __restrict__ state,
                                              const float* __restrict__ W1,
                                              const float* __restrict__ W2,
                                              const float* __restrict__ Wq1,
                                              u16* __restrict__ state_b, u16* __restrict__ W1t,
                                              u16* __restrict__ W2t, u16* __restrict__ Wq1at,
                                              u16* __restrict__ ENCt) {
    int i = blockIdx.x * 256 + threadIdx.x;
    if (i < PREP_STATE) { state_b[i] = f2bf(state[i]); return; }
    i -= PREP_STATE;
    if (i < PREP_W1T) { int h = i >> 5, k = i & 31; W1t[i] = f2bf(W1[k * NH + h]); return; }
    i -= PREP_W1T;
    if (i < PREP_W2T) { int e = i >> 8, h = i & 255; W2t[i] = f2bf(W2[h * NE + e]); return; }
    i -= PREP_W2T;
    if (i < PREP_WQ1T) { int hq = i >> 7, e = i & 127; Wq1at[i] = f2bf(Wq1[e * NH + hq]); return; }
    i -= PREP_WQ1T;
    if (i < PREP_PAD) { int eb = i >> 4, mm = NN + (i & 15); ENCt[(size_t)eb * KP + mm] = 0; }
}

// ---------------------------------------------------------------- bf16 NT MFMA GEMM, 64x128 tile, BK=32
// C = A[M][K] * (Bt[N][K])^T ; out bf16. BMODE: 0 none, 1 bias[col], 2 bias[row].
// PERM (enc2 only): col=(b*2000+m) -> store at ((b*128 + row)*KP + m)   [(b,e) row order]
template<int RELU, int BMODE, int RSC, int PERM>
__global__ __launch_bounds__(256) void mfma_gemm(
        const u16* __restrict__ A, const u16* __restrict__ Bt, u16* __restrict__ C,
        int M, int N, int K, int lda, int ldb, int ldc,
        const float* __restrict__ bias, const float* __restrict__ rowScale) {
    __shared__ u16 lds[12 * 512];           // 12 chunks x 1KB (A: 0-3, B: 4-11)
    const int tid = threadIdx.x;
    const int w = tid >> 6, l = tid & 63;
    const int wr = w & 1, wc = w >> 1;
    const int bm = blockIdx.x * 64, bn = blockIdx.y * 128;
    const int lm = l & 15, lq = l >> 4;

    f32x4 acc[2][4] = {};

    for (int k0 = 0; k0 < K; k0 += 32) {
        __syncthreads();
#pragma unroll
        for (int i = 0; i < 3; ++i) {
            const int idx = w * 3 + i;
            const u16* gp;
            if (idx < 4) {
                int row = bm + idx * 16 + lm;
                row = row < M ? row : M - 1;
                gp = A + (size_t)row * lda + k0 + lq * 8;
            } else {
                const int col = bn + (idx - 4) * 16 + lm;
                gp = Bt + (size_t)col * ldb + k0 + lq * 8;
            }
            __builtin_amdgcn_global_load_lds((gptr_t)gp, (lptr_t)(lds + idx * 512), 16, 0, 0);
        }
        __syncthreads();
        b16x8 af[2], bf[4];
#pragma unroll
        for (int i = 0; i < 2; ++i) af[i] = *(const b16x8*)(lds + (wr * 2 + i) * 512 + l * 8);
#pragma unroll
        for (int j = 0; j < 4; ++j) bf[j] = *(const b16x8*)(lds + (4 + wc * 4 + j) * 512 + l * 8);
#pragma unroll
        for (int i = 0; i < 2; ++i)
#pragma unroll
            for (int j = 0; j < 4; ++j)
                acc[i][j] = __builtin_amdgcn_mfma_f32_16x16x32_bf16(af[i], bf[j], acc[i][j], 0, 0, 0);
    }

#pragma unroll
    for (int i = 0; i < 2; ++i) {
#pragma unroll
        for (int r = 0; r < 4; ++r) {
            const int row = bm + wr * 32 + i * 16 + lq * 4 + r;
            if (row >= M) continue;
            const float rsv = RSC ? rowScale[row] : 1.0f;
#pragma unroll
            for (int j = 0; j < 4; ++j) {
                const int col = bn + wc * 64 + j * 16 + lm;
                float v = acc[i][j][r] * rsv;
                if (BMODE == 1) v += bias[col];
                if (BMODE == 2) v += bias[row];
                if (RELU) v = fmaxf(v, 0.0f);
                size_t addr;
                if (PERM) {
                    const unsigned bb = (unsigned)col / 2000u;
                    const unsigned mm = (unsigned)col - bb * 2000u;
                    addr = ((size_t)bb * 128 + row) * KP + mm;
                } else {
                    addr = (size_t)row * ldc + col;
                }
                C[addr] = f2bf(v);
            }
        }
    }
}

// ---------------------------------------------------------------- cooperative 8-agent loop
// grid 512 x 256. Phase A: 2048 waves, wave wg: b=wg&31, ngroup=wg>>5;
// rows n=ngroup+64k. Local (sum e, sum e*n) then 2 atomicAdds. Phase B: blocks 0-31.
__global__ __launch_bounds__(256, 2) void k_loop(
        const u16* __restrict__ y0, const float* __restrict__ Wq1,
        const float* __restrict__ Wq2, const float* __restrict__ bq2,
        float* actions, float* ap, float* s1, float* s2, float* out) {
    cg::grid_group grid = cg::this_grid();
    __shared__ float sh[256];
    __shared__ float act_sh[NA];
    const int lane = threadIdx.x & 63;
    const int wg = blockIdx.x * 4 + (threadIdx.x >> 6);
    const int b = wg & 31;
    const int ng = wg >> 5;                 // 0..63
    const float4 w4 = *(const float4*)(Wq2 + lane * 4);

    for (int ag = 0; ag < NA; ++ag) {
        // ---- phase A: softmax partials over nodes
        const float4 a4 = *(const float4*)(ap + b * NH + lane * 4);
        float se = 0.0f, sn = 0.0f;
        for (int n = ng; n < NN; n += 64) {
            const uint2 yv = *(const uint2*)(y0 + ((size_t)n * NB + b) * NH + lane * 4);
            float q = fmaxf(__uint_as_float(yv.x << 16) + a4.x, 0.f) * w4.x
                    + fmaxf(__uint_as_float(yv.x & 0xFFFF0000u) + a4.y, 0.f) * w4.y
                    + fmaxf(__uint_as_float(yv.y << 16) + a4.z, 0.f) * w4.z
                    + fmaxf(__uint_as_float(yv.y & 0xFFFF0000u) + a4.w, 0.f) * w4.w;
#pragma unroll
            for (int off = 32; off > 0; off >>= 1) q += __shfl_down(q, off);
            if (lane == 0) {
                const float e = expf(fminf(q, 60.0f));
                se += e; sn += e * (float)n;
            }
        }
        if (lane == 0) { atomicAdd(&s1[b], se); atomicAdd(&s2[b], sn); }
        grid.sync();
        // ---- phase B: blocks 0..31 finalize agent ag
        if (blockIdx.x < NB) {
            const int bb = blockIdx.x, t = threadIdx.x;
            const float sam = fminf(fmaxf(s2[bb] / s1[bb], 0.0f), 2000.0f);
            const float samn = sam * (1.0f / ACTION_NORM);
            if (t < NA) act_sh[t] = (t == ag) ? samn : actions[bb * NA + t];
            __syncthreads();
            if (t == 0) actions[bb * NA + ag] = samn;
            float apv = 0.0f;
#pragma unroll
            for (int a = 0; a < NA; ++a)
                apv = fmaf(act_sh[a], Wq1[(size_t)(NE + a) * NH + t], apv);
            ap[bb * NH + t] = apv;          // for next agent's phase A
            int nsel = (int)sam; if (nsel > NN - 1) nsel = NN - 1;
            const float yv = bf2f(y0[((size_t)nsel * NB + bb) * NH + t]);
            sh[t] = fmaxf(yv + apv, 0.0f) * Wq2[t];
            __syncthreads();
            for (int s = 128; s > 0; s >>= 1) {
                if (t < s) sh[t] += sh[t + s];
                __syncthreads();
            }
            if (t == 0) {
                out[bb * NA + ag] = sh[0] + bq2[0];
                s1[bb] = 0.0f; s2[bb] = 0.0f;   // reset for next agent
            }
        }
        grid.sync();
    }
    // chosen actions
    if (blockIdx.x < NB && threadIdx.x < NA)
        out[NB * NA + blockIdx.x * NA + threadIdx.x] =
            (float)(int)(actions[blockIdx.x * NA + threadIdx.x] * ACTION_NORM);
}

// ---------------------------------------------------------------- launch
extern "C" void kernel_launch(void* const* d_in, const int* in_sizes, int n_in,
                              void* d_out, int out_size, void* d_ws, size_t ws_size,
                              hipStream_t stream) {
    const float* state = (const float*)d_in[0];
    const float* dm    = (const float*)d_in[1];
    const float* W1    = (const float*)d_in[2];
    const float* b1    = (const float*)d_in[3];
    const float* W2    = (const float*)d_in[4];
    const float* b2    = (const float*)d_in[5];
    const float* Wq1   = (const float*)d_in[6];
    const float* bq1   = (const float*)d_in[7];
    const float* Wq2   = (const float*)d_in[8];
    const float* bq2   = (const float*)d_in[9];
    const int* fa      = (const int*)d_in[10];
    const int* fid     = (const int*)d_in[11];
    float* out = (float*)d_out;

    char* p = (char*)d_ws;
    u16* simb      = (u16*)p;      p += (size_t)NN * KP * 2;
    float* inv_rs  = (float*)p;    p += 2048 * 4;
    unsigned* dmax_u = (unsigned*)p; p += 256;
    float* actions = (float*)p;    p += 256 * 4;
    float* ap      = (float*)p;    p += 8192 * 4;
    float* s1      = (float*)p;    p += 64 * 4;
    float* s2      = (float*)p;    p += 64 * 4;
    u16* state_b   = (u16*)p;      p += (size_t)2048000 * 2;
    u16* W1t       = (u16*)p;      p += 8192 * 2;
    u16* W2t       = (u16*)p;      p += 32768 * 2;
    u16* Wq1at     = (u16*)p;      p += 32768 * 2;
    u16* h1        = (u16*)p;      p += (size_t)16384000 * 2;
    u16* ENCt      = (u16*)p;      p += (size_t)4096 * KP * 2;
    u16* Xt        = (u16*)p;      p += (size_t)8192000 * 2;   // conv out == y0-GEMM A
    u16* y0w       = (u16*)p;      p += (size_t)16384000 * 2;

    const int RTOT = NB * NN;  // 64000

    k_prep<<<(PREP_TOT + 255) / 256, 256, 0, stream>>>(state, W1, W2, Wq1,
                                                       state_b, W1t, W2t, Wq1at, ENCt);
    k_init<<<NB, 256, 0, stream>>>(dmax_u, actions, ap, s1, s2, fa, fid, Wq1);
    k_max<<<1024, 256, 0, stream>>>(dm, dmax_u, NN * NN);
    k_sim<<<NN, 256, 0, stream>>>(dm, dmax_u, simb, inv_rs);

    // enc1: h1 = relu(state @ W1 + b1)  [64000,256]
    mfma_gemm<1, 1, 0, 0><<<dim3(RTOT / 64, NH / 128), 256, 0, stream>>>(
        state_b, W1t, h1, RTOT, NH, NRD, NRD, NRD, NH, b1, nullptr);
    // enc2 (transposed out, (b,e) rows): ENCt[(b,e)][m] = (W2t @ h1^T) + b2[row]
    mfma_gemm<0, 2, 0, 1><<<dim3(NE / 64, RTOT / 128), 256, 0, stream>>>(
        W2t, h1, ENCt, NE, RTOT, NH, NH, NH, 0, b2, nullptr);
    // conv: Xt[(n,b)][e] = inv_rs[n] * (simb @ ENCt^T)  [2000 x 4096] row-major == Xt
    mfma_gemm<0, 0, 1, 0><<<dim3(32, 32), 256, 0, stream>>>(
        simb, ENCt, Xt, NN, NB * NE, KP, KP, KP, NB * NE, nullptr, inv_rs);
    // y0 = Xt @ Wq1[:128] + bq1  [64000,256]
    mfma_gemm<0, 1, 0, 0><<<dim3(RTOT / 64, NH / 128), 256, 0, stream>>>(
        Xt, Wq1at, y0w, RTOT, NH, NE, NE, NE, NH, bq1, nullptr);

    // fused 8-agent loop (cooperative)
    void* args[] = {(void*)&y0w, (void*)&Wq1, (void*)&Wq2, (void*)&bq2,
                    (void*)&actions, (void*)&ap, (void*)&s1, (void*)&s2, (void*)&out};
    hipLaunchCooperativeKernel((void*)k_loop, dim3(512), dim3(256), args, 0, stream);
}

// Round 4
// 332.650 us; speedup vs baseline: 3.8641x; 3.8641x over previous
//
#include <hip/hip_runtime.h>
#include <cstddef>

#define NB 32
#define NN 2000
#define NRD 32
#define NE 128
#define NH 256
#define NA 8
#define KP 2016          // conv K padded to multiple of 32
#define NG 128           // node groups per batch in k_agent
#define ACTION_NORM 2000.0f

typedef unsigned short u16;
typedef __bf16 b16x8 __attribute__((ext_vector_type(8)));
typedef float f32x4 __attribute__((ext_vector_type(4)));
typedef const __attribute__((address_space(1))) unsigned int* gptr_t;
typedef __attribute__((address_space(3))) unsigned int* lptr_t;

__device__ inline u16 f2bf(float x) {
    unsigned u = __float_as_uint(x);
    u += 0x7FFFu + ((u >> 16) & 1u);
    return (u16)(u >> 16);
}
__device__ inline float bf2f(u16 h) { return __uint_as_float((unsigned)h << 16); }

// ---------------------------------------------------------------- init: dmax reset + actions
__global__ __launch_bounds__(256) void k_init(unsigned* dmax_u, float* actions,
                                              const int* __restrict__ fa,
                                              const int* __restrict__ fid) {
    const int t = threadIdx.x;            // t = b*8 + a
    if (t == 0) *dmax_u = 0u;
    const int b = t >> 3, a = t & 7;
    float v = -1.0f;
    for (int j = 0; j < 3; ++j)
        if (fid[j] == a) v = (float)fa[j * NB + b] / ACTION_NORM;
    actions[t] = v;
}

// ---------------------------------------------------------------- global max of dm
__global__ __launch_bounds__(256) void k_max(const float* __restrict__ dm,
                                             unsigned* dmax_u, int n) {
    __shared__ float sh[256];
    float m = 0.0f;
    for (int i = blockIdx.x * blockDim.x + threadIdx.x; i < n; i += gridDim.x * blockDim.x)
        m = fmaxf(m, dm[i]);
    sh[threadIdx.x] = m; __syncthreads();
    for (int s = 128; s > 0; s >>= 1) {
        if (threadIdx.x < s) sh[threadIdx.x] = fmaxf(sh[threadIdx.x], sh[threadIdx.x + s]);
        __syncthreads();
    }
    if (threadIdx.x == 0) atomicMax(dmax_u, __float_as_uint(sh[0]));
}

// ---------------------------------------------------------------- sim rows -> bf16 (K padded), inv rowsum
__global__ __launch_bounds__(256) void k_sim(const float* __restrict__ dm,
                                             const unsigned* __restrict__ dmax_u,
                                             u16* __restrict__ simb,
                                             float* __restrict__ inv_rs) {
    __shared__ float sh[256];
    const int n = blockIdx.x;
    const float inv = 1.0f / __uint_as_float(*dmax_u);
    float s = 0.0f;
    for (int m = threadIdx.x; m < KP; m += 256) {
        if (m < NN) {
            float e = expf(-dm[(size_t)n * NN + m] * inv);
            simb[(size_t)n * KP + m] = f2bf(e);
            s += e;
        } else {
            simb[(size_t)n * KP + m] = 0;
        }
    }
    sh[threadIdx.x] = s; __syncthreads();
    for (int st = 128; st > 0; st >>= 1) {
        if (threadIdx.x < st) sh[threadIdx.x] += sh[threadIdx.x + st];
        __syncthreads();
    }
    if (threadIdx.x == 0) inv_rs[n] = 1.0f / sh[0];
}

// ---------------------------------------------------------------- prep: convert state, transpose weights, zero ENC pad
#define PREP_STATE (64000 * 32)
#define PREP_W1T   (256 * 32)
#define PREP_W2T   (128 * 256)
#define PREP_WQ1T  (256 * 128)
#define PREP_PAD   (4096 * 16)
#define PREP_TOT   (PREP_STATE + PREP_W1T + PREP_W2T + PREP_WQ1T + PREP_PAD)
__global__ __launch_bounds__(256) void k_prep(const float* __restrict__ state,
                                              const float* __restrict__ W1,
                                              const float* __restrict__ W2,
                                              const float* __restrict__ Wq1,
                                              u16* __restrict__ state_b, u16* __restrict__ W1t,
                                              u16* __restrict__ W2t, u16* __restrict__ Wq1at,
                                              u16* __restrict__ ENCt) {
    int i = blockIdx.x * 256 + threadIdx.x;
    if (i < PREP_STATE) { state_b[i] = f2bf(state[i]); return; }
    i -= PREP_STATE;
    if (i < PREP_W1T) { int h = i >> 5, k = i & 31; W1t[i] = f2bf(W1[k * NH + h]); return; }
    i -= PREP_W1T;
    if (i < PREP_W2T) { int e = i >> 8, h = i & 255; W2t[i] = f2bf(W2[h * NE + e]); return; }
    i -= PREP_W2T;
    if (i < PREP_WQ1T) { int hq = i >> 7, e = i & 127; Wq1at[i] = f2bf(Wq1[e * NH + hq]); return; }
    i -= PREP_WQ1T;
    if (i < PREP_PAD) { int eb = i >> 4, mm = NN + (i & 15); ENCt[(size_t)eb * KP + mm] = 0; }
}

// ---------------------------------------------------------------- bf16 NT MFMA GEMM, 128x128 tile, BK=32
// C = A[M][K] * (Bt[N][K])^T ; out bf16. BMODE: 0 none, 1 bias[col], 2 bias[row].
// PERM (enc2 only): col=(b*2000+m) -> store at ((b*128 + row)*KP + m)  [(b,e) row order]
template<int RELU, int BMODE, int RSC, int PERM>
__global__ __launch_bounds__(256) void mfma_gemm(
        const u16* __restrict__ A, const u16* __restrict__ Bt, u16* __restrict__ C,
        int M, int N, int K, int lda, int ldb, int ldc,
        const float* __restrict__ bias, const float* __restrict__ rowScale) {
    __shared__ u16 lds[16 * 512];           // 16 chunks x 1KB (A: 0-7, B: 8-15)
    const int tid = threadIdx.x;
    const int w = tid >> 6, l = tid & 63;
    const int wr = w & 1, wc = w >> 1;
    const int bm = blockIdx.x * 128, bn = blockIdx.y * 128;
    const int lm = l & 15, lq = l >> 4;

    f32x4 acc[4][4] = {};

    for (int k0 = 0; k0 < K; k0 += 32) {
        __syncthreads();
#pragma unroll
        for (int i = 0; i < 4; ++i) {
            const int idx = w * 4 + i;
            const u16* gp;
            if (idx < 8) {
                int row = bm + idx * 16 + lm;
                row = row < M ? row : M - 1;
                gp = A + (size_t)row * lda + k0 + lq * 8;
            } else {
                const int col = bn + (idx - 8) * 16 + lm;
                gp = Bt + (size_t)col * ldb + k0 + lq * 8;
            }
            __builtin_amdgcn_global_load_lds((gptr_t)gp, (lptr_t)(lds + idx * 512), 16, 0, 0);
        }
        __syncthreads();
        b16x8 af[4], bf[4];
#pragma unroll
        for (int i = 0; i < 4; ++i) {
            af[i] = *(const b16x8*)(lds + (wr * 4 + i) * 512 + l * 8);
            bf[i] = *(const b16x8*)(lds + (8 + wc * 4 + i) * 512 + l * 8);
        }
#pragma unroll
        for (int fr = 0; fr < 4; ++fr)
#pragma unroll
            for (int fc = 0; fc < 4; ++fc)
                acc[fr][fc] = __builtin_amdgcn_mfma_f32_16x16x32_bf16(af[fr], bf[fc], acc[fr][fc], 0, 0, 0);
    }

#pragma unroll
    for (int fr = 0; fr < 4; ++fr) {
#pragma unroll
        for (int r = 0; r < 4; ++r) {
            const int row = bm + wr * 64 + fr * 16 + lq * 4 + r;
            if (row >= M) continue;
            const float rsv = RSC ? rowScale[row] : 1.0f;
#pragma unroll
            for (int fc = 0; fc < 4; ++fc) {
                const int col = bn + wc * 64 + fc * 16 + lm;
                float v = acc[fr][fc][r] * rsv;
                if (BMODE == 1) v += bias[col];
                if (BMODE == 2) v += bias[row];
                if (RELU) v = fmaxf(v, 0.0f);
                size_t addr;
                if (PERM) {
                    const unsigned bb = (unsigned)col / 2000u;
                    const unsigned mm = (unsigned)col - bb * 2000u;
                    addr = ((size_t)bb * 128 + row) * KP + mm;
                } else {
                    addr = (size_t)row * ldc + col;
                }
                C[addr] = f2bf(v);
            }
        }
    }
}

// ---------------------------------------------------------------- per-agent kernel
// grid 512x256 = 2048 waves; wave wg: b=wg&31, ng=wg>>5 (0..127), rows n=ng+128k.
// Every wave recomputes sam(ag-1) from pin (bit-identical), derives its ap slice,
// accumulates softmax partials, writes ONE float2 to pout (no atomics).
// Blocks 0..31 additionally finalize agent ag-1 (q2 at nsel -> out, actions write).
__global__ __launch_bounds__(256) void k_agent(
        const u16* __restrict__ y0, const float* __restrict__ Wq1,
        const float* __restrict__ Wq2, const float* __restrict__ bq2,
        float* actions, const float2* __restrict__ pin, float2* __restrict__ pout,
        float* __restrict__ out, int ag) {
    __shared__ float sh[256];
    __shared__ float s_sam;
    const int t = threadIdx.x;
    const int lane = t & 63, wave = t >> 6;
    const int wg = blockIdx.x * 4 + wave;
    const int b = wg & 31, ng = wg >> 5;

    float act[NA];
#pragma unroll
    for (int a = 0; a < NA; ++a) act[a] = actions[b * NA + a];
    if (ag > 0) {
        const float2 p0 = pin[b * NG + lane];
        const float2 p1 = pin[b * NG + 64 + lane];
        float se0 = p0.x + p1.x, sn0 = p0.y + p1.y;
#pragma unroll
        for (int m = 32; m > 0; m >>= 1) {
            se0 += __shfl_xor(se0, m); sn0 += __shfl_xor(sn0, m);
        }
        const float sam = fminf(fmaxf(sn0 / se0, 0.0f), 2000.0f);
        act[ag - 1] = sam * (1.0f / ACTION_NORM);
    }
    float4 apv = make_float4(0.f, 0.f, 0.f, 0.f);
#pragma unroll
    for (int a = 0; a < NA; ++a) {
        const float4 wq = *(const float4*)(Wq1 + (size_t)(NE + a) * NH + lane * 4);
        apv.x = fmaf(act[a], wq.x, apv.x);
        apv.y = fmaf(act[a], wq.y, apv.y);
        apv.z = fmaf(act[a], wq.z, apv.z);
        apv.w = fmaf(act[a], wq.w, apv.w);
    }
    const float4 w4 = *(const float4*)(Wq2 + lane * 4);

    float se = 0.0f, sn = 0.0f;
    for (int n = ng; n < NN; n += NG) {
        const uint2 yv = *(const uint2*)(y0 + ((size_t)n * NB + b) * NH + lane * 4);
        float q = fmaxf(__uint_as_float(yv.x << 16) + apv.x, 0.f) * w4.x
                + fmaxf(__uint_as_float(yv.x & 0xFFFF0000u) + apv.y, 0.f) * w4.y
                + fmaxf(__uint_as_float(yv.y << 16) + apv.z, 0.f) * w4.z
                + fmaxf(__uint_as_float(yv.y & 0xFFFF0000u) + apv.w, 0.f) * w4.w;
#pragma unroll
        for (int off = 32; off > 0; off >>= 1) q += __shfl_down(q, off);
        if (lane == 0) {
            const float e = expf(fminf(q, 60.0f));
            se += e; sn += e * (float)n;
        }
    }
    if (lane == 0) pout[b * NG + ng] = make_float2(se, sn);

    if (ag > 0 && blockIdx.x < NB) {
        const int bb = blockIdx.x;
        if (wave == 0) {
            const float2 p0 = pin[bb * NG + lane];
            const float2 p1 = pin[bb * NG + 64 + lane];
            float a1 = p0.x + p1.x, a2 = p0.y + p1.y;
#pragma unroll
            for (int m = 32; m > 0; m >>= 1) {
                a1 += __shfl_xor(a1, m); a2 += __shfl_xor(a2, m);
            }
            if (lane == 0) s_sam = fminf(fmaxf(a2 / a1, 0.0f), 2000.0f);
        }
        __syncthreads();
        const float sam = s_sam;
        const float samn = sam * (1.0f / ACTION_NORM);
        float apt = 0.0f;
#pragma unroll
        for (int a = 0; a < NA; ++a) {
            const float av = (a == ag - 1) ? samn : actions[bb * NA + a];
            apt = fmaf(av, Wq1[(size_t)(NE + a) * NH + t], apt);
        }
        int nsel = (int)sam; if (nsel > NN - 1) nsel = NN - 1;
        const float yv = bf2f(y0[((size_t)nsel * NB + bb) * NH + t]);
        sh[t] = fmaxf(yv + apt, 0.0f) * Wq2[t];
        __syncthreads();
        for (int s = 128; s > 0; s >>= 1) {
            if (t < s) sh[t] += sh[t + s];
            __syncthreads();
        }
        if (t == 0) {
            out[bb * NA + (ag - 1)] = sh[0] + bq2[0];
            actions[bb * NA + (ag - 1)] = samn;
        }
    }
}

// ---------------------------------------------------------------- tail: finalize agent 7 + chosen
__global__ __launch_bounds__(256) void k_fin(
        const u16* __restrict__ y0, const float* __restrict__ Wq1,
        const float* __restrict__ Wq2, const float* __restrict__ bq2,
        const float* __restrict__ actions, const float2* __restrict__ pin,
        float* __restrict__ out) {
    __shared__ float sh[256];
    __shared__ float s_sam;
    const int bb = blockIdx.x, t = threadIdx.x;
    const int lane = t & 63, wave = t >> 6;
    if (wave == 0) {
        const float2 p0 = pin[bb * NG + lane];
        const float2 p1 = pin[bb * NG + 64 + lane];
        float a1 = p0.x + p1.x, a2 = p0.y + p1.y;
#pragma unroll
        for (int m = 32; m > 0; m >>= 1) {
            a1 += __shfl_xor(a1, m); a2 += __shfl_xor(a2, m);
        }
        if (lane == 0) s_sam = fminf(fmaxf(a2 / a1, 0.0f), 2000.0f);
    }
    __syncthreads();
    const float sam = s_sam;
    const float samn = sam * (1.0f / ACTION_NORM);
    float apt = 0.0f;
#pragma unroll
    for (int a = 0; a < NA; ++a) {
        const float av = (a == NA - 1) ? samn : actions[bb * NA + a];
        apt = fmaf(av, Wq1[(size_t)(NE + a) * NH + t], apt);
    }
    int nsel = (int)sam; if (nsel > NN - 1) nsel = NN - 1;
    const float yv = bf2f(y0[((size_t)nsel * NB + bb) * NH + t]);
    sh[t] = fmaxf(yv + apt, 0.0f) * Wq2[t];
    __syncthreads();
    for (int s = 128; s > 0; s >>= 1) {
        if (t < s) sh[t] += sh[t + s];
        __syncthreads();
    }
    if (t == 0) out[bb * NA + (NA - 1)] = sh[0] + bq2[0];
    if (t < NA) {
        const float av = (t == NA - 1) ? samn : actions[bb * NA + t];
        out[NB * NA + bb * NA + t] = (float)(int)(av * ACTION_NORM);
    }
}

// ---------------------------------------------------------------- launch
extern "C" void kernel_launch(void* const* d_in, const int* in_sizes, int n_in,
                              void* d_out, int out_size, void* d_ws, size_t ws_size,
                              hipStream_t stream) {
    const float* state = (const float*)d_in[0];
    const float* dm    = (const float*)d_in[1];
    const float* W1    = (const float*)d_in[2];
    const float* b1    = (const float*)d_in[3];
    const float* W2    = (const float*)d_in[4];
    const float* b2    = (const float*)d_in[5];
    const float* Wq1   = (const float*)d_in[6];
    const float* bq1   = (const float*)d_in[7];
    const float* Wq2   = (const float*)d_in[8];
    const float* bq2   = (const float*)d_in[9];
    const int* fa      = (const int*)d_in[10];
    const int* fid     = (const int*)d_in[11];
    float* out = (float*)d_out;

    char* p = (char*)d_ws;
    u16* simb      = (u16*)p;      p += (size_t)NN * KP * 2;
    float* inv_rs  = (float*)p;    p += 2048 * 4;
    unsigned* dmax_u = (unsigned*)p; p += 256;
    float* actions = (float*)p;    p += 256 * 4;
    float2* part0  = (float2*)p;   p += (size_t)NB * NG * 8;
    float2* part1  = (float2*)p;   p += (size_t)NB * NG * 8;
    u16* state_b   = (u16*)p;      p += (size_t)2048000 * 2;
    u16* W1t       = (u16*)p;      p += 8192 * 2;
    u16* W2t       = (u16*)p;      p += 32768 * 2;
    u16* Wq1at     = (u16*)p;      p += 32768 * 2;
    u16* h1        = (u16*)p;      p += (size_t)16384000 * 2;
    u16* ENCt      = (u16*)p;      p += (size_t)4096 * KP * 2;
    u16* Xt        = (u16*)p;      p += (size_t)8192000 * 2;   // conv out == y0-GEMM A
    u16* y0w       = (u16*)p;      p += (size_t)16384000 * 2;

    const int RTOT = NB * NN;  // 64000

    k_prep<<<(PREP_TOT + 255) / 256, 256, 0, stream>>>(state, W1, W2, Wq1,
                                                       state_b, W1t, W2t, Wq1at, ENCt);
    k_init<<<1, 256, 0, stream>>>(dmax_u, actions, fa, fid);
    k_max<<<1024, 256, 0, stream>>>(dm, dmax_u, NN * NN);
    k_sim<<<NN, 256, 0, stream>>>(dm, dmax_u, simb, inv_rs);

    // enc1: h1 = relu(state @ W1 + b1)  [64000,256]
    mfma_gemm<1, 1, 0, 0><<<dim3(RTOT / 128, NH / 128), 256, 0, stream>>>(
        state_b, W1t, h1, RTOT, NH, NRD, NRD, NRD, NH, b1, nullptr);
    // enc2 (transposed out, (b,e) rows): ENCt[(b,e)][m] = (W2t @ h1^T) + b2[row]
    mfma_gemm<0, 2, 0, 1><<<dim3(1, RTOT / 128), 256, 0, stream>>>(
        W2t, h1, ENCt, NE, RTOT, NH, NH, NH, 0, b2, nullptr);
    // conv: Xt[(n,b)][e] = inv_rs[n] * (simb @ ENCt^T)  [2000 x 4096] row-major == Xt
    mfma_gemm<0, 0, 1, 0><<<dim3(16, 32), 256, 0, stream>>>(
        simb, ENCt, Xt, NN, NB * NE, KP, KP, KP, NB * NE, nullptr, inv_rs);
    // y0 = Xt @ Wq1[:128] + bq1  [64000,256]
    mfma_gemm<0, 1, 0, 0><<<dim3(RTOT / 128, NH / 128), 256, 0, stream>>>(
        Xt, Wq1at, y0w, RTOT, NH, NE, NE, NE, NH, bq1, nullptr);

    // 8-agent loop: one kernel per agent, double-buffered partials
    for (int ag = 0; ag < NA; ++ag) {
        const float2* pin  = (ag & 1) ? part0 : part1;
        float2*       pout = (ag & 1) ? part1 : part0;
        k_agent<<<512, 256, 0, stream>>>(y0w, Wq1, Wq2, bq2, actions,
                                         pin, pout, out, ag);
    }
    // finalize agent 7 (+ chosen); its partials are in part1 (ag=7 wrote part1)
    k_fin<<<NB, 256, 0, stream>>>(y0w, Wq1, Wq2, bq2, actions, part1, out);
}